// Round 1
// baseline (2219.888 us; speedup 1.0000x reference)
//
#include <hip/hip_runtime.h>
#include <hip/hip_bf16.h>

#define B_ 32
#define S_ 1024
#define D_ 512
#define P_ 20
#define G_ 80   // 4*P

__device__ __forceinline__ float sigm_f(float x) { return 1.f / (1.f + __expf(-x)); }
__device__ __forceinline__ float tanh_f(float x) { return 1.f - 2.f / (__expf(2.f * x) + 1.f); }

// ---------------- K1: XW[r][g] = x[r,:] @ W_ih[g,:] + b_ih[g] + b_hh[g] ----------------
// block: 256 threads handles 8 rows of x (staged in LDS), 80 cols
__global__ __launch_bounds__(256) void xw_kernel(const float* __restrict__ x,
                                                 const float* __restrict__ W_ih,
                                                 const float* __restrict__ b_ih,
                                                 const float* __restrict__ b_hh,
                                                 float* __restrict__ xw) {
    __shared__ float xs[8][D_];
    const int r0 = blockIdx.x * 8;
    const float4* xg = (const float4*)(x + (size_t)r0 * D_);
    float4* xsv = (float4*)&xs[0][0];
#pragma unroll
    for (int i = 0; i < 4; ++i) xsv[threadIdx.x + i * 256] = xg[threadIdx.x + i * 256];
    __syncthreads();

    for (int o = threadIdx.x; o < 8 * G_; o += 256) {
        const int r = o / G_;
        const int g = o - r * G_;
        const float4* wrow = (const float4*)(W_ih + (size_t)g * D_);
        const float4* xrow = (const float4*)&xs[r][0];
        float acc = 0.f;
#pragma unroll 8
        for (int k4 = 0; k4 < D_ / 4; ++k4) {
            float4 a = xrow[k4];
            float4 w = wrow[k4];
            acc += a.x * w.x + a.y * w.y + a.z * w.z + a.w * w.w;
        }
        xw[(size_t)(r0 + r) * G_ + g] = acc + b_ih[g] + b_hh[g];
    }
}

// ---------------- K2: sequential LSTM + heads + mu recurrence ----------------
// one wave (64 threads) per batch element.
// lane p<20: computes gates i,f,g,o for hidden unit p (W_hh rows in registers)
// lanes 20..22: mu head rows; lane 23: sigma head. heads run one step lagged.
__global__ __launch_bounds__(64) void lstm_kernel(const float* __restrict__ xw,
                                                  const float* __restrict__ W_hh,
                                                  const float* __restrict__ W_mu,
                                                  const float* __restrict__ b_mu,
                                                  const float* __restrict__ W_sig,
                                                  const float* __restrict__ b_sig,
                                                  const int* __restrict__ pad,
                                                  float* __restrict__ mus,
                                                  float* __restrict__ sigma) {
    const int b = blockIdx.x;
    const int l = threadIdx.x;
    __shared__ float hs[P_];
    __shared__ float scratch[3];

    float A[P_], Bv[P_], C[P_], Dv[P_];
#pragma unroll
    for (int q = 0; q < P_; ++q) { A[q] = 0.f; Bv[q] = 0.f; C[q] = 0.f; Dv[q] = 0.f; }
    if (l < P_) {
#pragma unroll
        for (int q = 0; q < P_; ++q) {
            A[q]  = W_hh[(0 * P_ + l) * P_ + q];
            Bv[q] = W_hh[(1 * P_ + l) * P_ + q];
            C[q]  = W_hh[(2 * P_ + l) * P_ + q];
            Dv[q] = W_hh[(3 * P_ + l) * P_ + q];
        }
    } else if (l < 23) {
#pragma unroll
        for (int q = 0; q < P_; ++q) A[q] = W_mu[(l - 20) * P_ + q];
    } else if (l == 23) {
#pragma unroll
        for (int q = 0; q < P_; ++q) A[q] = W_sig[q];
    }
    float c_reg = 0.f;
    if (l < P_) hs[l] = 0.f;
    const float invL = 1.f / (float)pad[b];
    const float bmu = (l >= 20 && l < 23) ? b_mu[l - 20] : 0.f;
    const float bsg = b_sig[0];
    float mu_prev = 0.f;
    const float* xwb = xw + (size_t)b * S_ * G_;
    __syncthreads();

    for (int t = 0; t <= S_; ++t) {
        // prefetch xw for this step
        float xi = 0.f, xf = 0.f, xg = 0.f, xo = 0.f;
        if (l < P_ && t < S_) {
            const float* r = xwb + t * G_;
            xi = r[l]; xf = r[P_ + l]; xg = r[2 * P_ + l]; xo = r[3 * P_ + l];
        }
        // dots over current h (= h_{t-1})
        float d1 = 0.f, d2 = 0.f, d3 = 0.f, d4 = 0.f;
#pragma unroll
        for (int q = 0; q < P_; ++q) {
            float hq = hs[q];
            d1 += A[q] * hq; d2 += Bv[q] * hq; d3 += C[q] * hq; d4 += Dv[q] * hq;
        }
        __syncthreads();  // all hs reads done before overwrite
        if (l < P_ && t < S_) {
            float ig = sigm_f(d1 + xi);
            float fg = sigm_f(d2 + xf);
            float gg = tanh_f(d3 + xg);
            float og = sigm_f(d4 + xo);
            c_reg = fg * c_reg + ig * gg;
            hs[l] = og * tanh_f(c_reg);
        }
        if (t > 0) {
            if (l >= 20 && l < 23) scratch[l - 20] = fmaxf(d1 + bmu, 0.f);
            else if (l == 23) sigma[(size_t)b * S_ + (t - 1)] = sigm_f(d1 + bsg);
        }
        __syncthreads();  // hs + scratch visible
        if (l == 0 && t > 0) {
            float j = (float)(t - 1);
            float m = scratch[0] * mu_prev + (scratch[1] + scratch[2] * (j + 1.f)) * invL;
            m = fmaxf(m, j * invL);
            mu_prev = m;
            mus[(size_t)b * S_ + (t - 1)] = m;
        }
    }
}

// ---------------- K3: causal Gaussian attention, fp32 ----------------
// block: 256 threads handles (b, 32-row j-tile) x full D.
// thread t: jg = t>>6 (4 j-groups of 8), d0 = (t&63)*8 (8 contiguous d per thread)
__global__ __launch_bounds__(256) void attn_kernel(const float* __restrict__ x,
                                                   const float* __restrict__ mus,
                                                   const float* __restrict__ sigma,
                                                   const int* __restrict__ pad,
                                                   float* __restrict__ out) {
    __shared__ float wt[32][33];
    __shared__ float rowsum[32];
    __shared__ float muv[32];
    __shared__ float i2s[32];

    const int jt = (gridDim.x - 1) - blockIdx.x;  // heavy tiles first
    const int b = blockIdx.y;
    const int j0 = jt * 32;
    const int t = threadIdx.x;
    const float invL = 1.f / (float)pad[b];

    if (t < 32) {
        float m = mus[(size_t)b * S_ + j0 + t];
        float sg = sigma[(size_t)b * S_ + j0 + t];
        muv[t] = m;
        i2s[t] = 1.f / (2.f * sg * sg + 0.001f);
        rowsum[t] = 0.f;
    }
    __syncthreads();

    const int jg = t >> 6;          // 0..3
    const int d0 = (t & 63) * 8;    // 0..504
    const int jw = t & 31;          // w-gen row
    const int kw0 = t >> 5;         // w-gen k base (0..7)

    float acc[8][8];
#pragma unroll
    for (int a = 0; a < 8; ++a)
#pragma unroll
        for (int d = 0; d < 8; ++d) acc[a][d] = 0.f;

    const float mju = muv[jw];
    const float isj = i2s[jw];

    for (int kt = 0; kt <= jt; ++kt) {
        const int k0 = kt * 32;
        // --- generate w tile ---
        float part = 0.f;
#pragma unroll
        for (int m = 0; m < 4; ++m) {
            const int kk = kw0 + m * 8;
            const int k = k0 + kk;
            float dd = (float)k * invL - mju;
            float w = (k <= j0 + jw) ? __expf(-dd * dd * isj) : 0.f;
            wt[jw][kk] = w;
            part += w;
        }
        atomicAdd(&rowsum[jw], part);
        __syncthreads();
        // --- MAC ---
        const float* xb = x + ((size_t)b * S_ + k0) * D_ + d0;
#pragma unroll 4
        for (int kk = 0; kk < 32; ++kk) {
            const float4 xa = *(const float4*)(xb + (size_t)kk * D_);
            const float4 xc = *(const float4*)(xb + (size_t)kk * D_ + 4);
#pragma unroll
            for (int jj = 0; jj < 8; ++jj) {
                const float w = wt[jg * 8 + jj][kk];
                acc[jj][0] += w * xa.x; acc[jj][1] += w * xa.y;
                acc[jj][2] += w * xa.z; acc[jj][3] += w * xa.w;
                acc[jj][4] += w * xc.x; acc[jj][5] += w * xc.y;
                acc[jj][6] += w * xc.z; acc[jj][7] += w * xc.w;
            }
        }
        __syncthreads();
    }

    // --- normalize + store ---
    float* ob = out + ((size_t)b * S_ + j0) * D_ + d0;
#pragma unroll
    for (int jj = 0; jj < 8; ++jj) {
        const int jl = jg * 8 + jj;
        const float r = 1.f / fmaxf(rowsum[jl], 1e-12f);
        float4 o1, o2;
        o1.x = acc[jj][0] * r; o1.y = acc[jj][1] * r; o1.z = acc[jj][2] * r; o1.w = acc[jj][3] * r;
        o2.x = acc[jj][4] * r; o2.y = acc[jj][5] * r; o2.z = acc[jj][6] * r; o2.w = acc[jj][7] * r;
        *(float4*)(ob + (size_t)jl * D_) = o1;
        *(float4*)(ob + (size_t)jl * D_ + 4) = o2;
    }
}

extern "C" void kernel_launch(void* const* d_in, const int* in_sizes, int n_in,
                              void* d_out, int out_size, void* d_ws, size_t ws_size,
                              hipStream_t stream) {
    const float* x     = (const float*)d_in[0];
    const int*   pad   = (const int*)d_in[1];
    const float* W_ih  = (const float*)d_in[2];
    const float* W_hh  = (const float*)d_in[3];
    const float* b_ih  = (const float*)d_in[4];
    const float* b_hh  = (const float*)d_in[5];
    const float* W_mu  = (const float*)d_in[6];
    const float* b_mu  = (const float*)d_in[7];
    const float* W_sig = (const float*)d_in[8];
    const float* b_sig = (const float*)d_in[9];
    float* out = (float*)d_out;

    float* xw    = (float*)d_ws;                       // B*S*80 floats
    float* mus   = xw + (size_t)B_ * S_ * G_;          // B*S floats
    float* sigma = mus + (size_t)B_ * S_;              // B*S floats

    xw_kernel<<<(B_ * S_) / 8, 256, 0, stream>>>(x, W_ih, b_ih, b_hh, xw);
    lstm_kernel<<<B_, 64, 0, stream>>>(xw, W_hh, W_mu, b_mu, W_sig, b_sig, pad, mus, sigma);
    attn_kernel<<<dim3(S_ / 32, B_), 256, 0, stream>>>(x, mus, sigma, pad, out);
}

// Round 3
// 1756.756 us; speedup vs baseline: 1.2636x; 1.2636x over previous
//
#include <hip/hip_runtime.h>
#include <hip/hip_bf16.h>

#define B_ 32
#define S_ 1024
#define D_ 512
#define P_ 20
#define G_ 80   // 4*P

typedef __attribute__((ext_vector_type(8))) short short8v;
typedef __attribute__((ext_vector_type(4))) float f32x4;

__device__ __forceinline__ float sigm_f(float x) { return 1.f / (1.f + __expf(-x)); }
__device__ __forceinline__ float tanh_f(float x) { return 1.f - 2.f / (__expf(2.f * x) + 1.f); }
__device__ __forceinline__ unsigned short f2bf(float f) {
    unsigned int u = __float_as_uint(f);
    u += 0x7FFF + ((u >> 16) & 1);   // RNE; inputs are finite
    return (unsigned short)(u >> 16);
}

// ---------------- K1: XW[r][g] = x[r,:] @ W_ih[g,:] + b_ih[g] + b_hh[g] ----------------
__global__ __launch_bounds__(256) void xw_kernel(const float* __restrict__ x,
                                                 const float* __restrict__ W_ih,
                                                 const float* __restrict__ b_ih,
                                                 const float* __restrict__ b_hh,
                                                 float* __restrict__ xw) {
    __shared__ float xs[8][D_];
    const int r0 = blockIdx.x * 8;
    const float4* xg = (const float4*)(x + (size_t)r0 * D_);
    float4* xsv = (float4*)&xs[0][0];
#pragma unroll
    for (int i = 0; i < 4; ++i) xsv[threadIdx.x + i * 256] = xg[threadIdx.x + i * 256];
    __syncthreads();

    for (int o = threadIdx.x; o < 8 * G_; o += 256) {
        const int r = o / G_;
        const int g = o - r * G_;
        const float4* wrow = (const float4*)(W_ih + (size_t)g * D_);
        const float4* xrow = (const float4*)&xs[r][0];
        float acc = 0.f;
#pragma unroll 8
        for (int k4 = 0; k4 < D_ / 4; ++k4) {
            float4 a = xrow[k4];
            float4 w = wrow[k4];
            acc += a.x * w.x + a.y * w.y + a.z * w.z + a.w * w.w;
        }
        xw[(size_t)(r0 + r) * G_ + g] = acc + b_ih[g] + b_hh[g];
    }
}

// ---------------- K1b: transpose x -> xT[b][d][s] in bf16 ----------------
__global__ __launch_bounds__(256) void conv_kernel(const float* __restrict__ x,
                                                   unsigned short* __restrict__ xT) {
    __shared__ unsigned short tile[64][80];  // [d_local][s_local], padded
    const int b = blockIdx.z;
    const int s0 = blockIdx.x * 64;
    const int d0 = blockIdx.y * 64;
    const int t = threadIdx.x;
    const int r = t >> 2;            // s row 0..63
    const int c0 = (t & 3) * 16;     // d col base

    const float4* src = (const float4*)(x + ((size_t)(b * S_ + s0 + r)) * D_ + d0 + c0);
    float4 v0 = src[0], v1 = src[1], v2 = src[2], v3 = src[3];
    float vv[16] = {v0.x, v0.y, v0.z, v0.w, v1.x, v1.y, v1.z, v1.w,
                    v2.x, v2.y, v2.z, v2.w, v3.x, v3.y, v3.z, v3.w};
#pragma unroll
    for (int e = 0; e < 16; ++e) tile[c0 + e][r] = f2bf(vv[e]);
    __syncthreads();

    const int dr = t >> 2;           // d row 0..63
    const int sc = (t & 3) * 16;     // s col base
    const unsigned short* tr = &tile[dr][sc];
    uint4 w0 = *(const uint4*)(tr);
    uint4 w1 = *(const uint4*)(tr + 8);
    uint4* dst = (uint4*)(xT + ((size_t)(b * D_ + d0 + dr)) * S_ + s0 + sc);
    dst[0] = w0;
    dst[1] = w1;
}

// ---------------- K2: wave-synchronous LSTM + heads + mu recurrence ----------------
// one wave per batch. lane p<20: hidden unit p; lanes 20-22: mu head; lane 23: sigma head.
// No barriers: h broadcast via __shfl (wave-level), xw prefetched 2 steps ahead.
__global__ __launch_bounds__(64) void lstm_kernel(const float* __restrict__ xw,
                                                  const float* __restrict__ W_hh,
                                                  const float* __restrict__ W_mu,
                                                  const float* __restrict__ b_mu,
                                                  const float* __restrict__ W_sig,
                                                  const float* __restrict__ b_sig,
                                                  const int* __restrict__ pad,
                                                  float* __restrict__ mus,
                                                  float* __restrict__ sigma) {
    const int b = blockIdx.x;
    const int l = threadIdx.x;

    float A[P_], Bv[P_], C[P_], Dv[P_];
#pragma unroll
    for (int q = 0; q < P_; ++q) { A[q] = 0.f; Bv[q] = 0.f; C[q] = 0.f; Dv[q] = 0.f; }
    if (l < P_) {
#pragma unroll
        for (int q = 0; q < P_; ++q) {
            A[q]  = W_hh[(0 * P_ + l) * P_ + q];
            Bv[q] = W_hh[(1 * P_ + l) * P_ + q];
            C[q]  = W_hh[(2 * P_ + l) * P_ + q];
            Dv[q] = W_hh[(3 * P_ + l) * P_ + q];
        }
    } else if (l < 23) {
#pragma unroll
        for (int q = 0; q < P_; ++q) A[q] = W_mu[(l - 20) * P_ + q];
    } else if (l == 23) {
#pragma unroll
        for (int q = 0; q < P_; ++q) A[q] = W_sig[q];
    }

    const float invL = 1.f / (float)pad[b];
    const float bmu = (l >= 20 && l < 23) ? b_mu[l - 20] : 0.f;
    const float bsg = b_sig[0];
    float h = 0.f, c = 0.f, mu_prev = 0.f;
    const float* xwb = xw + (size_t)b * S_ * G_;
    const bool act = (l < P_);

    // prefetch xw[0], xw[1]
    float xi0 = 0.f, xf0 = 0.f, xg0 = 0.f, xo0 = 0.f;
    float xi1 = 0.f, xf1 = 0.f, xg1 = 0.f, xo1 = 0.f;
    if (act) {
        xi0 = xwb[l]; xf0 = xwb[P_ + l]; xg0 = xwb[2 * P_ + l]; xo0 = xwb[3 * P_ + l];
        const float* r1 = xwb + G_;
        xi1 = r1[l]; xf1 = r1[P_ + l]; xg1 = r1[2 * P_ + l]; xo1 = r1[3 * P_ + l];
    }

    for (int t = 0; t <= S_; ++t) {
        // broadcast h (value after t gate updates == pw[t-1] for t>=1)
        float hq[P_];
#pragma unroll
        for (int q = 0; q < P_; ++q) hq[q] = __shfl(h, q);

        // 4 dots, each as 2 partial chains to halve dependent-FMA latency
        float p1 = 0.f, p2 = 0.f, p3 = 0.f, p4 = 0.f;
        float q1 = 0.f, q2 = 0.f, q3 = 0.f, q4 = 0.f;
#pragma unroll
        for (int q = 0; q < P_ / 2; ++q) {
            p1 += A[q] * hq[q];  p2 += Bv[q] * hq[q];
            p3 += C[q] * hq[q];  p4 += Dv[q] * hq[q];
            q1 += A[q + 10] * hq[q + 10];  q2 += Bv[q + 10] * hq[q + 10];
            q3 += C[q + 10] * hq[q + 10];  q4 += Dv[q + 10] * hq[q + 10];
        }
        const float d1 = p1 + q1, d2 = p2 + q2, d3 = p3 + q3, d4 = p4 + q4;

        if (act && t < S_) {
            float ig = sigm_f(d1 + xi0);
            float fg = sigm_f(d2 + xf0);
            float gg = tanh_f(d3 + xg0);
            float og = sigm_f(d4 + xo0);
            c = fg * c + ig * gg;
            h = og * tanh_f(c);
            // rotate prefetch
            xi0 = xi1; xf0 = xf1; xg0 = xg1; xo0 = xo1;
            if (t + 2 < S_) {
                const float* r = xwb + (size_t)(t + 2) * G_;
                xi1 = r[l]; xf1 = r[P_ + l]; xg1 = r[2 * P_ + l]; xo1 = r[3 * P_ + l];
            }
        }
        if (t > 0) {
            float rv = fmaxf(d1 + bmu, 0.f);               // lanes 20-22: mu head rows
            if (l == 23) sigma[(size_t)b * S_ + (t - 1)] = sigm_f(d1 + bsg);
            float s0 = __shfl(rv, 20);
            float s1 = __shfl(rv, 21);
            float s2 = __shfl(rv, 22);
            if (l == 0) {
                float j = (float)(t - 1);
                float m = s0 * mu_prev + (s1 + s2 * (j + 1.f)) * invL;
                m = fmaxf(m, j * invL);
                mu_prev = m;
                mus[(size_t)b * S_ + (t - 1)] = m;
            }
        }
    }
}

// ---------------- K3: causal Gaussian attention via MFMA bf16 ----------------
// block: (b, 64-row j-tile), 4 waves; wave w owns j rows [jt*64+w*16, +16), all 512 d.
// A = w[j][k] generated in-register (lane: j=l&15 row, 8 contiguous k at (l>>4)*8).
// B = x[k][d] loaded from xT[b][d][s]: lane l reads 16B contiguous (8 k) for d col l&15.
__global__ __launch_bounds__(256, 2) void attn_kernel(const unsigned short* __restrict__ xT,
                                                      const float* __restrict__ mus,
                                                      const float* __restrict__ sigma,
                                                      const int* __restrict__ pad,
                                                      float* __restrict__ out) {
    const int jt = (gridDim.x - 1) - blockIdx.x;  // heavy tiles dispatch first
    const int b = blockIdx.y;
    const int tid = threadIdx.x;
    const int w = tid >> 6;
    const int l = tid & 63;
    const int lo = l & 15, hi = l >> 4;
    const int jw0 = jt * 64 + w * 16;
    const float invL = 1.f / (float)pad[b];

    const int jA = jw0 + lo;                       // this lane's w-row
    const float mu = mus[(size_t)b * S_ + jA];
    const float sg = sigma[(size_t)b * S_ + jA];
    const float nis = -1.f / (2.f * sg * sg + 0.001f);

    f32x4 acc[32];
#pragma unroll
    for (int dt = 0; dt < 32; ++dt) acc[dt] = (f32x4){0.f, 0.f, 0.f, 0.f};

    const unsigned short* xb = xT + (size_t)b * D_ * S_ + (size_t)lo * S_ + hi * 8;
    float rs = 0.f;
    const int kend = (jt + 1) * 64;

    for (int k0 = 0; k0 < kend; k0 += 32) {
        // generate A fragment (w tile slice) + partial row-sum
        short8v a;
#pragma unroll
        for (int e = 0; e < 8; ++e) {
            const int k = k0 + hi * 8 + e;
            const float dd = (float)k * invL - mu;
            const float wv = (k <= jA) ? __expf(dd * dd * nis) : 0.f;
            rs += wv;
            a[e] = (short)f2bf(wv);
        }
#pragma unroll
        for (int dt = 0; dt < 32; ++dt) {
            const short8v bfrag = *(const short8v*)(xb + (size_t)dt * 16 * S_ + k0);
            acc[dt] = __builtin_amdgcn_mfma_f32_16x16x32_bf16(a, bfrag, acc[dt], 0, 0, 0);
        }
    }

    // row-sums: lanes {lo, lo+16, lo+32, lo+48} hold partials of row jw0+lo
    rs += __shfl_xor(rs, 16);
    rs += __shfl_xor(rs, 32);
    __shared__ float rsm[4][16];
    if (l < 16) rsm[w][l] = rs;
    __syncthreads();

    // store: C/D layout row=(l>>4)*4+r (j), col=l&15 (d)
#pragma unroll
    for (int r = 0; r < 4; ++r) {
        const int j = jw0 + hi * 4 + r;
        const float rcp = 1.f / fmaxf(rsm[w][hi * 4 + r], 1e-12f);
        float* ob = out + ((size_t)b * S_ + j) * D_ + lo;
#pragma unroll
        for (int dt = 0; dt < 32; ++dt) {
            ob[dt * 16] = acc[dt][r] * rcp;
        }
    }
}

extern "C" void kernel_launch(void* const* d_in, const int* in_sizes, int n_in,
                              void* d_out, int out_size, void* d_ws, size_t ws_size,
                              hipStream_t stream) {
    const float* x     = (const float*)d_in[0];
    const int*   pad   = (const int*)d_in[1];
    const float* W_ih  = (const float*)d_in[2];
    const float* W_hh  = (const float*)d_in[3];
    const float* b_ih  = (const float*)d_in[4];
    const float* b_hh  = (const float*)d_in[5];
    const float* W_mu  = (const float*)d_in[6];
    const float* b_mu  = (const float*)d_in[7];
    const float* W_sig = (const float*)d_in[8];
    const float* b_sig = (const float*)d_in[9];
    float* out = (float*)d_out;

    float* xw    = (float*)d_ws;                        // B*S*80 f32   (10.5 MB)
    float* mus   = xw + (size_t)B_ * S_ * G_;           // B*S f32
    float* sigma = mus + (size_t)B_ * S_;               // B*S f32
    unsigned short* xT = (unsigned short*)(sigma + (size_t)B_ * S_);  // B*D*S bf16 (32 MB)

    xw_kernel<<<(B_ * S_) / 8, 256, 0, stream>>>(x, W_ih, b_ih, b_hh, xw);
    conv_kernel<<<dim3(S_ / 64, D_ / 64, B_), 256, 0, stream>>>(x, xT);
    lstm_kernel<<<B_, 64, 0, stream>>>(xw, W_hh, W_mu, b_mu, W_sig, b_sig, pad, mus, sigma);
    attn_kernel<<<dim3(S_ / 64, B_), 256, 0, stream>>>(xT, mus, sigma, pad, out);
}

// Round 4
// 956.971 us; speedup vs baseline: 2.3197x; 1.8357x over previous
//
#include <hip/hip_runtime.h>
#include <hip/hip_bf16.h>

#define B_ 32
#define S_ 1024
#define D_ 512
#define P_ 20
#define G_ 80   // 4*P

typedef __attribute__((ext_vector_type(8))) short short8v;
typedef __attribute__((ext_vector_type(4))) float f32x4;

__device__ __forceinline__ float sigm_f(float x) { return 1.f / (1.f + __expf(-x)); }
__device__ __forceinline__ float tanh_f(float x) { return 1.f - 2.f / (__expf(2.f * x) + 1.f); }
__device__ __forceinline__ unsigned short f2bf(float f) {
    unsigned int u = __float_as_uint(f);
    u += 0x7FFF + ((u >> 16) & 1);   // RNE; inputs are finite
    return (unsigned short)(u >> 16);
}
__device__ __forceinline__ float bcast(float v, int lane) {
    return __uint_as_float(__builtin_amdgcn_readlane(__float_as_uint(v), lane));
}
__device__ __forceinline__ short8v cvt8(float4 p, float4 q) {
    union { __hip_bfloat162 h2[4]; short8v s; } u;
    u.h2[0] = __float22bfloat162_rn(float2{p.x, p.y});
    u.h2[1] = __float22bfloat162_rn(float2{p.z, p.w});
    u.h2[2] = __float22bfloat162_rn(float2{q.x, q.y});
    u.h2[3] = __float22bfloat162_rn(float2{q.z, q.w});
    return u.s;
}

// ---------------- K1: xw = x @ W_ih^T + b_ih + b_hh  via MFMA bf16 ----------------
// block = 64 rows (4 waves x 16), wave computes 16 rows x 80 g over K=512.
// A frag: lane holds x[row=l&15][k=(l>>4)*8+e]; B frag: lane holds W_ih[g=n*16+(l&15)][k].
__global__ __launch_bounds__(256) void xw_kernel(const float* __restrict__ x,
                                                 const float* __restrict__ W_ih,
                                                 const float* __restrict__ b_ih,
                                                 const float* __restrict__ b_hh,
                                                 float* __restrict__ xw) {
    const int tid = threadIdx.x;
    const int w = tid >> 6, l = tid & 63;
    const int lo = l & 15, hi = l >> 4;
    const int m0 = blockIdx.x * 64 + w * 16;

    f32x4 acc[5];
#pragma unroll
    for (int n = 0; n < 5; ++n) acc[n] = (f32x4){0.f, 0.f, 0.f, 0.f};

    const float* xrow = x + (size_t)(m0 + lo) * D_ + hi * 8;
#pragma unroll 4
    for (int k0 = 0; k0 < D_; k0 += 32) {
        const float4 a0 = *(const float4*)(xrow + k0);
        const float4 a1 = *(const float4*)(xrow + k0 + 4);
        const short8v a = cvt8(a0, a1);
#pragma unroll
        for (int n = 0; n < 5; ++n) {
            const float* wr = W_ih + (size_t)(n * 16 + lo) * D_ + k0 + hi * 8;
            const float4 b0 = *(const float4*)(wr);
            const float4 b1 = *(const float4*)(wr + 4);
            const short8v bf = cvt8(b0, b1);
            acc[n] = __builtin_amdgcn_mfma_f32_16x16x32_bf16(a, bf, acc[n], 0, 0, 0);
        }
    }
    // D layout: row=(l>>4)*4+r, col=l&15
#pragma unroll
    for (int n = 0; n < 5; ++n) {
        const int g = n * 16 + lo;
        const float bias = b_ih[g] + b_hh[g];
#pragma unroll
        for (int r = 0; r < 4; ++r) {
            const int m = m0 + hi * 4 + r;
            xw[(size_t)m * G_ + g] = acc[n][r] + bias;
        }
    }
}

// ---------------- K1b: transpose x -> xT[b][d][s] in bf16 ----------------
__global__ __launch_bounds__(256) void conv_kernel(const float* __restrict__ x,
                                                   unsigned short* __restrict__ xT) {
    __shared__ unsigned short tile[64][80];
    const int b = blockIdx.z;
    const int s0 = blockIdx.x * 64;
    const int d0 = blockIdx.y * 64;
    const int t = threadIdx.x;
    const int r = t >> 2;
    const int c0 = (t & 3) * 16;

    const float4* src = (const float4*)(x + ((size_t)(b * S_ + s0 + r)) * D_ + d0 + c0);
    float4 v0 = src[0], v1 = src[1], v2 = src[2], v3 = src[3];
    float vv[16] = {v0.x, v0.y, v0.z, v0.w, v1.x, v1.y, v1.z, v1.w,
                    v2.x, v2.y, v2.z, v2.w, v3.x, v3.y, v3.z, v3.w};
#pragma unroll
    for (int e = 0; e < 16; ++e) tile[c0 + e][r] = f2bf(vv[e]);
    __syncthreads();

    const int dr = t >> 2;
    const int sc = (t & 3) * 16;
    const unsigned short* tr = &tile[dr][sc];
    uint4 w0 = *(const uint4*)(tr);
    uint4 w1 = *(const uint4*)(tr + 8);
    uint4* dst = (uint4*)(xT + ((size_t)(b * D_ + d0 + dr)) * S_ + s0 + sc);
    dst[0] = w0;
    dst[1] = w1;
}

// ---------------- K2: wave-synchronous LSTM, 8-deep register prefetch ----------------
__global__ __launch_bounds__(64) void lstm_kernel(const float* __restrict__ xw,
                                                  const float* __restrict__ W_hh,
                                                  const float* __restrict__ W_mu,
                                                  const float* __restrict__ b_mu,
                                                  const float* __restrict__ W_sig,
                                                  const float* __restrict__ b_sig,
                                                  const int* __restrict__ pad,
                                                  float* __restrict__ mus,
                                                  float* __restrict__ sigma) {
    const int b = blockIdx.x;
    const int l = threadIdx.x;

    float A[P_], Bv[P_], C[P_], Dv[P_];
#pragma unroll
    for (int q = 0; q < P_; ++q) { A[q] = 0.f; Bv[q] = 0.f; C[q] = 0.f; Dv[q] = 0.f; }
    if (l < P_) {
#pragma unroll
        for (int q = 0; q < P_; ++q) {
            A[q]  = W_hh[(0 * P_ + l) * P_ + q];
            Bv[q] = W_hh[(1 * P_ + l) * P_ + q];
            C[q]  = W_hh[(2 * P_ + l) * P_ + q];
            Dv[q] = W_hh[(3 * P_ + l) * P_ + q];
        }
    } else if (l < 23) {
#pragma unroll
        for (int q = 0; q < P_; ++q) A[q] = W_mu[(l - 20) * P_ + q];
    } else if (l == 23) {
#pragma unroll
        for (int q = 0; q < P_; ++q) A[q] = W_sig[q];
    }

    const float invL = 1.f / (float)pad[b];
    const float bmu = (l >= 20 && l < 23) ? b_mu[l - 20] : 0.f;
    const float bsg = b_sig[0];
    float h = 0.f, c = 0.f, mu_prev = 0.f;
    const float* xwb = xw + (size_t)b * S_ * G_;
    const bool act = (l < P_);

    // 8-deep prefetch ring (static-indexed via full unroll)
    float ri[8], rf[8], rg[8], ro[8];
#pragma unroll
    for (int u = 0; u < 8; ++u) {
        ri[u] = rf[u] = rg[u] = ro[u] = 0.f;
        if (act) {
            const float* r = xwb + (size_t)u * G_;
            ri[u] = r[l]; rf[u] = r[P_ + l]; rg[u] = r[2 * P_ + l]; ro[u] = r[3 * P_ + l];
        }
    }

    for (int T = 0; T < S_; T += 8) {
#pragma unroll
        for (int u = 0; u < 8; ++u) {
            const int t = T + u;
            // broadcast h (pre-update = pw[t-1]) to SGPRs
            float hq[P_];
#pragma unroll
            for (int q = 0; q < P_; ++q) hq[q] = bcast(h, q);

            float p1 = 0.f, p2 = 0.f, p3 = 0.f, p4 = 0.f;
            float q1 = 0.f, q2 = 0.f, q3 = 0.f, q4 = 0.f;
#pragma unroll
            for (int q = 0; q < P_ / 2; ++q) {
                p1 += A[q] * hq[q];           p2 += Bv[q] * hq[q];
                p3 += C[q] * hq[q];           p4 += Dv[q] * hq[q];
                q1 += A[q + 10] * hq[q + 10]; q2 += Bv[q + 10] * hq[q + 10];
                q3 += C[q + 10] * hq[q + 10]; q4 += Dv[q + 10] * hq[q + 10];
            }
            const float d1 = p1 + q1, d2 = p2 + q2, d3 = p3 + q3, d4 = p4 + q4;

            if (act) {
                float ig = sigm_f(d1 + ri[u]);
                float fg = sigm_f(d2 + rf[u]);
                float gg = tanh_f(d3 + rg[u]);
                float og = sigm_f(d4 + ro[u]);
                c = fg * c + ig * gg;
                h = og * tanh_f(c);
                if (t + 8 < S_) {   // refill slot u for step t+8
                    const float* r = xwb + (size_t)(t + 8) * G_;
                    ri[u] = r[l]; rf[u] = r[P_ + l]; rg[u] = r[2 * P_ + l]; ro[u] = r[3 * P_ + l];
                }
            }
            if (t > 0) {
                const float rv = fmaxf(d1 + bmu, 0.f);
                if (l == 23) sigma[(size_t)b * S_ + (t - 1)] = sigm_f(d1 + bsg);
                const float s0 = bcast(rv, 20);
                const float s1 = bcast(rv, 21);
                const float s2 = bcast(rv, 22);
                if (l == 0) {
                    const float j = (float)(t - 1);
                    float m = s0 * mu_prev + (s1 + s2 * (j + 1.f)) * invL;
                    m = fmaxf(m, j * invL);
                    mu_prev = m;
                    mus[(size_t)b * S_ + (t - 1)] = m;
                }
            }
        }
    }
    // final head flush (t == S_, output index S_-1) using h = pw[S_-1]
    {
        float hq[P_];
#pragma unroll
        for (int q = 0; q < P_; ++q) hq[q] = bcast(h, q);
        float p1 = 0.f, q1 = 0.f;
#pragma unroll
        for (int q = 0; q < P_ / 2; ++q) {
            p1 += A[q] * hq[q];
            q1 += A[q + 10] * hq[q + 10];
        }
        const float d1 = p1 + q1;
        const float rv = fmaxf(d1 + bmu, 0.f);
        if (l == 23) sigma[(size_t)b * S_ + (S_ - 1)] = sigm_f(d1 + bsg);
        const float s0 = bcast(rv, 20);
        const float s1 = bcast(rv, 21);
        const float s2 = bcast(rv, 22);
        if (l == 0) {
            const float j = (float)(S_ - 1);
            float m = s0 * mu_prev + (s1 + s2 * (j + 1.f)) * invL;
            m = fmaxf(m, j * invL);
            mus[(size_t)b * S_ + (S_ - 1)] = m;
        }
    }
}

// ---------------- K3: causal Gaussian attention, MFMA bf16 + LDS-staged B ----------------
// block: (b, 64-row j-tile), 4 waves. x-tile (32k x 512d) staged in LDS, shared by waves.
// LDS rows stride 40 shorts (80 B): 16B-aligned, bank-optimal for the b128 frag reads.
__global__ __launch_bounds__(256, 2) void attn_kernel(const unsigned short* __restrict__ xT,
                                                      const float* __restrict__ mus,
                                                      const float* __restrict__ sigma,
                                                      const int* __restrict__ pad,
                                                      float* __restrict__ out) {
    __shared__ unsigned short xt[D_][40];   // 40 KB
    __shared__ float rsm[4][16];

    const int jt = (gridDim.x - 1) - blockIdx.x;  // heavy tiles dispatch first
    const int b = blockIdx.y;
    const int tid = threadIdx.x;
    const int w = tid >> 6;
    const int l = tid & 63;
    const int lo = l & 15, hi = l >> 4;
    const int jw0 = jt * 64 + w * 16;
    const float invL = 1.f / (float)pad[b];

    const int jA = jw0 + lo;
    const float mu = mus[(size_t)b * S_ + jA];
    const float sg = sigma[(size_t)b * S_ + jA];
    const float nis = -1.f / (2.f * sg * sg + 0.001f);

    f32x4 acc[32];
#pragma unroll
    for (int dt = 0; dt < 32; ++dt) acc[dt] = (f32x4){0.f, 0.f, 0.f, 0.f};

    const unsigned short* xTb = xT + (size_t)b * D_ * S_;
    float rs = 0.f;
    const int kend = (jt + 1) * 64;

    for (int k0 = 0; k0 < kend; k0 += 32) {
        // issue next tile's global loads (2 rows x 64 B per thread) before the barrier
        uint4 v[2][4];
#pragma unroll
        for (int rr = 0; rr < 2; ++rr) {
            const int d = tid + rr * 256;
            const uint4* src = (const uint4*)(xTb + (size_t)d * S_ + k0);
#pragma unroll
            for (int i = 0; i < 4; ++i) v[rr][i] = src[i];
        }
        __syncthreads();   // previous iteration's reads complete
#pragma unroll
        for (int rr = 0; rr < 2; ++rr) {
            const int d = tid + rr * 256;
#pragma unroll
            for (int i = 0; i < 4; ++i) *(uint4*)&xt[d][i * 8] = v[rr][i];
        }
        __syncthreads();   // tile visible

        // A fragment (Gaussian weights) + partial row-sum
        short8v a;
#pragma unroll
        for (int e = 0; e < 8; ++e) {
            const int k = k0 + hi * 8 + e;
            const float dd = (float)k * invL - mu;
            const float wv = (k <= jA) ? __expf(dd * dd * nis) : 0.f;
            rs += wv;
            a[e] = (short)f2bf(wv);
        }
#pragma unroll
        for (int dt = 0; dt < 32; ++dt) {
            const short8v bf = *(const short8v*)&xt[dt * 16 + lo][hi * 8];
            acc[dt] = __builtin_amdgcn_mfma_f32_16x16x32_bf16(a, bf, acc[dt], 0, 0, 0);
        }
    }

    rs += __shfl_xor(rs, 16);
    rs += __shfl_xor(rs, 32);
    if (l < 16) rsm[w][l] = rs;
    __syncthreads();

#pragma unroll
    for (int r = 0; r < 4; ++r) {
        const int j = jw0 + hi * 4 + r;
        const float rcp = 1.f / fmaxf(rsm[w][hi * 4 + r], 1e-12f);
        float* ob = out + ((size_t)b * S_ + j) * D_ + lo;
#pragma unroll
        for (int dt = 0; dt < 32; ++dt) {
            ob[dt * 16] = acc[dt][r] * rcp;
        }
    }
}

extern "C" void kernel_launch(void* const* d_in, const int* in_sizes, int n_in,
                              void* d_out, int out_size, void* d_ws, size_t ws_size,
                              hipStream_t stream) {
    const float* x     = (const float*)d_in[0];
    const int*   pad   = (const int*)d_in[1];
    const float* W_ih  = (const float*)d_in[2];
    const float* W_hh  = (const float*)d_in[3];
    const float* b_ih  = (const float*)d_in[4];
    const float* b_hh  = (const float*)d_in[5];
    const float* W_mu  = (const float*)d_in[6];
    const float* b_mu  = (const float*)d_in[7];
    const float* W_sig = (const float*)d_in[8];
    const float* b_sig = (const float*)d_in[9];
    float* out = (float*)d_out;

    float* xw    = (float*)d_ws;                        // B*S*80 f32
    float* mus   = xw + (size_t)B_ * S_ * G_;           // B*S f32
    float* sigma = mus + (size_t)B_ * S_;               // B*S f32
    unsigned short* xT = (unsigned short*)(sigma + (size_t)B_ * S_);  // B*D*S bf16

    xw_kernel<<<(B_ * S_) / 64, 256, 0, stream>>>(x, W_ih, b_ih, b_hh, xw);
    conv_kernel<<<dim3(S_ / 64, D_ / 64, B_), 256, 0, stream>>>(x, xT);
    lstm_kernel<<<B_, 64, 0, stream>>>(xw, W_hh, W_mu, b_mu, W_sig, b_sig, pad, mus, sigma);
    attn_kernel<<<dim3(S_ / 64, B_), 256, 0, stream>>>(xT, mus, sigma, pad, out);
}

// Round 5
// 753.412 us; speedup vs baseline: 2.9464x; 1.2702x over previous
//
#include <hip/hip_runtime.h>
#include <hip/hip_bf16.h>

#define B_ 32
#define S_ 1024
#define D_ 512
#define P_ 20
#define G_ 80   // 4*P

typedef __attribute__((ext_vector_type(8))) short short8v;
typedef __attribute__((ext_vector_type(4))) float f32x4;

__device__ __forceinline__ float sigm_f(float x) { return 1.f / (1.f + __expf(-x)); }
__device__ __forceinline__ float tanh_f(float x) { return 1.f - 2.f / (__expf(2.f * x) + 1.f); }
__device__ __forceinline__ unsigned short f2bf(float f) {
    unsigned int u = __float_as_uint(f);
    u += 0x7FFF + ((u >> 16) & 1);   // RNE; inputs are finite
    return (unsigned short)(u >> 16);
}
__device__ __forceinline__ float bcast(float v, int lane) {
    return __uint_as_float(__builtin_amdgcn_readlane(__float_as_uint(v), lane));
}
__device__ __forceinline__ short8v cvt8(float4 p, float4 q) {
    union { __hip_bfloat162 h2[4]; short8v s; } u;
    u.h2[0] = __float22bfloat162_rn(float2{p.x, p.y});
    u.h2[1] = __float22bfloat162_rn(float2{p.z, p.w});
    u.h2[2] = __float22bfloat162_rn(float2{q.x, q.y});
    u.h2[3] = __float22bfloat162_rn(float2{q.z, q.w});
    return u.s;
}

// ---------------- K1: xw = x @ W_ih^T + b_ih + b_hh  via MFMA bf16 ----------------
__global__ __launch_bounds__(256) void xw_kernel(const float* __restrict__ x,
                                                 const float* __restrict__ W_ih,
                                                 const float* __restrict__ b_ih,
                                                 const float* __restrict__ b_hh,
                                                 float* __restrict__ xw) {
    const int tid = threadIdx.x;
    const int w = tid >> 6, l = tid & 63;
    const int lo = l & 15, hi = l >> 4;
    const int m0 = blockIdx.x * 64 + w * 16;

    f32x4 acc[5];
#pragma unroll
    for (int n = 0; n < 5; ++n) acc[n] = (f32x4){0.f, 0.f, 0.f, 0.f};

    const float* xrow = x + (size_t)(m0 + lo) * D_ + hi * 8;
#pragma unroll 4
    for (int k0 = 0; k0 < D_; k0 += 32) {
        const float4 a0 = *(const float4*)(xrow + k0);
        const float4 a1 = *(const float4*)(xrow + k0 + 4);
        const short8v a = cvt8(a0, a1);
#pragma unroll
        for (int n = 0; n < 5; ++n) {
            const float* wr = W_ih + (size_t)(n * 16 + lo) * D_ + k0 + hi * 8;
            const float4 b0 = *(const float4*)(wr);
            const float4 b1 = *(const float4*)(wr + 4);
            const short8v bf = cvt8(b0, b1);
            acc[n] = __builtin_amdgcn_mfma_f32_16x16x32_bf16(a, bf, acc[n], 0, 0, 0);
        }
    }
#pragma unroll
    for (int n = 0; n < 5; ++n) {
        const int g = n * 16 + lo;
        const float bias = b_ih[g] + b_hh[g];
#pragma unroll
        for (int r = 0; r < 4; ++r) {
            const int m = m0 + hi * 4 + r;
            xw[(size_t)m * G_ + g] = acc[n][r] + bias;
        }
    }
}

// ---------------- K1b: transpose x -> xT[b][d][s] in bf16 ----------------
__global__ __launch_bounds__(256) void conv_kernel(const float* __restrict__ x,
                                                   unsigned short* __restrict__ xT) {
    __shared__ unsigned short tile[64][80];
    const int b = blockIdx.z;
    const int s0 = blockIdx.x * 64;
    const int d0 = blockIdx.y * 64;
    const int t = threadIdx.x;
    const int r = t >> 2;
    const int c0 = (t & 3) * 16;

    const float4* src = (const float4*)(x + ((size_t)(b * S_ + s0 + r)) * D_ + d0 + c0);
    float4 v0 = src[0], v1 = src[1], v2 = src[2], v3 = src[3];
    float vv[16] = {v0.x, v0.y, v0.z, v0.w, v1.x, v1.y, v1.z, v1.w,
                    v2.x, v2.y, v2.z, v2.w, v3.x, v3.y, v3.z, v3.w};
#pragma unroll
    for (int e = 0; e < 16; ++e) tile[c0 + e][r] = f2bf(vv[e]);
    __syncthreads();

    const int dr = t >> 2;
    const int sc = (t & 3) * 16;
    const unsigned short* tr = &tile[dr][sc];
    uint4 w0 = *(const uint4*)(tr);
    uint4 w1 = *(const uint4*)(tr + 8);
    uint4* dst = (uint4*)(xT + ((size_t)(b * D_ + d0 + dr)) * S_ + s0 + sc);
    dst[0] = w0;
    dst[1] = w1;
}

// ---------------- K2: split-gate wave-synchronous LSTM ----------------
// lanes 0-19:  unit p=l, dots for gates (i, f)
// lanes 32-51: unit p=l-32, dots for gates (g, o)  [tanh via 2*sigm(2x)-1]
// lanes 20-22: mu head rows; lane 23: sigma head (bias via hb, no loads)
// mus/sigma buffered in LDS (lgkmcnt domain) -> vmcnt queue stays pure loads.
__global__ __launch_bounds__(64) void lstm_kernel(const float* __restrict__ xw,
                                                  const float* __restrict__ W_hh,
                                                  const float* __restrict__ W_mu,
                                                  const float* __restrict__ b_mu,
                                                  const float* __restrict__ W_sig,
                                                  const float* __restrict__ b_sig,
                                                  const int* __restrict__ pad,
                                                  float* __restrict__ mus,
                                                  float* __restrict__ sigma) {
    const int b = blockIdx.x;
    const int l = threadIdx.x;
    __shared__ float mbuf[S_];
    __shared__ float sbuf[S_];

    // per-lane dot coefficients
    float E[P_], F[P_];
#pragma unroll
    for (int q = 0; q < P_; ++q) { E[q] = 0.f; F[q] = 0.f; }
    if (l < P_) {
#pragma unroll
        for (int q = 0; q < P_; ++q) {
            E[q] = W_hh[(0 * P_ + l) * P_ + q];   // i row
            F[q] = W_hh[(1 * P_ + l) * P_ + q];   // f row
        }
    } else if (l < 23) {
#pragma unroll
        for (int q = 0; q < P_; ++q) E[q] = W_mu[(l - 20) * P_ + q];
    } else if (l == 23) {
#pragma unroll
        for (int q = 0; q < P_; ++q) E[q] = W_sig[q];
    } else if (l >= 32 && l < 32 + P_) {
        const int p = l - 32;
#pragma unroll
        for (int q = 0; q < P_; ++q) {
            E[q] = W_hh[(2 * P_ + p) * P_ + q];   // g row
            F[q] = W_hh[(3 * P_ + p) * P_ + q];   // o row
        }
    }

    const float invL = 1.f / (float)pad[b];
    // head bias constant (in arg1 path); activation constants for tanh-as-sigmoid
    const float hb = (l >= 20 && l < 23) ? b_mu[l - 20] : (l == 23 ? b_sig[0] : 0.f);
    const float ka = (l >= 32) ? 2.f : 1.f;
    const float Ka = (l >= 32) ? 2.f : 1.f;
    const float Kb = (l >= 32) ? -1.f : 0.f;
    const bool ld = (l < P_) || (l >= 32 && l < 32 + P_);
    const int o1 = (l < 32) ? l : (2 * P_ + (l - 32));          // i or g column
    const int o2 = (l < 32) ? (P_ + l) : (3 * P_ + (l - 32));   // f or o column

    float h = 0.f, c = 0.f, mu_prev = 0.f;
    const float* xwb = xw + (size_t)b * S_ * G_;

    // 8-deep prefetch ring
    float ri[8], rf[8];
#pragma unroll
    for (int u = 0; u < 8; ++u) {
        ri[u] = 0.f; rf[u] = 0.f;
        if (ld) {
            const float* r = xwb + (size_t)u * G_;
            ri[u] = r[o1]; rf[u] = r[o2];
        }
    }

    for (int T = 0; T < S_; T += 8) {
#pragma unroll
        for (int u = 0; u < 8; ++u) {
            const int t = T + u;
            // broadcast h (= pw[t-1]) into SGPRs
            float hq[P_];
#pragma unroll
            for (int q = 0; q < P_; ++q) hq[q] = bcast(h, q);

            float pa = 0.f, pb = 0.f, qa = 0.f, qb = 0.f;
#pragma unroll
            for (int q = 0; q < P_ / 2; ++q) {
                pa += E[q] * hq[q];            qa += F[q] * hq[q];
                pb += E[q + 10] * hq[q + 10];  qb += F[q + 10] * hq[q + 10];
            }
            const float d1 = pa + pb, d2 = qa + qb;
            const float arg1 = d1 + ri[u] + hb;
            const float arg2 = d2 + rf[u];

            const float s1 = sigm_f(ka * arg1);
            const float a1 = Ka * s1 + Kb;          // sigm (lo) / tanh (hi)
            const float a2 = sigm_f(arg2);
            const float rv = fmaxf(arg1, 0.f);      // relu for mu head lanes

            const float gx = __shfl_xor(a1, 32);    // partner's a1 (g for lo lanes)
            const float ox = __shfl_xor(a2, 32);    // partner's a2 (o for lo lanes)

            // lanes<20: c = f*c + i*g ; h = o*tanh(c). harmless garbage elsewhere.
            c = a2 * c + a1 * gx;
            h = ox * tanh_f(c);

            if (ld && t + 8 < S_) {   // refill slot u
                const float* r = xwb + (size_t)(t + 8) * G_;
                ri[u] = r[o1]; rf[u] = r[o2];
            }
            if (t > 0) {
                if (l == 23) sbuf[t - 1] = s1;       // sigm(d1 + b_sig)
                const float s0v = bcast(rv, 20);
                const float s1v = bcast(rv, 21);
                const float s2v = bcast(rv, 22);
                if (l == 0) {
                    const float j = (float)(t - 1);
                    float m = s0v * mu_prev + (s1v + s2v * (j + 1.f)) * invL;
                    m = fmaxf(m, j * invL);
                    mu_prev = m;
                    mbuf[t - 1] = m;
                }
            }
        }
    }
    // final head flush (j = S_-1) from final h
    {
        float hq[P_];
#pragma unroll
        for (int q = 0; q < P_; ++q) hq[q] = bcast(h, q);
        float pa = 0.f, pb = 0.f;
#pragma unroll
        for (int q = 0; q < P_ / 2; ++q) {
            pa += E[q] * hq[q];
            pb += E[q + 10] * hq[q + 10];
        }
        const float arg1 = pa + pb + hb;
        if (l == 23) sbuf[S_ - 1] = sigm_f(arg1);
        const float rv = fmaxf(arg1, 0.f);
        const float s0v = bcast(rv, 20);
        const float s1v = bcast(rv, 21);
        const float s2v = bcast(rv, 22);
        if (l == 0) {
            const float j = (float)(S_ - 1);
            float m = s0v * mu_prev + (s1v + s2v * (j + 1.f)) * invL;
            m = fmaxf(m, j * invL);
            mbuf[S_ - 1] = m;
        }
    }
    // coalesced flush (single wave: ds ordering via lgkmcnt, no barrier needed)
    __builtin_amdgcn_s_waitcnt(0);  // drain lds writes (lgkmcnt)
#pragma unroll
    for (int i = 0; i < S_ / (64 * 4); ++i) {
        const int idx = (i * 64 + l) * 4;
        *(float4*)&mus[(size_t)b * S_ + idx] = *(const float4*)&mbuf[idx];
        *(float4*)&sigma[(size_t)b * S_ + idx] = *(const float4*)&sbuf[idx];
    }
}

// ---------------- K3: causal Gaussian attention, MFMA bf16 + LDS-staged B ----------------
__global__ __launch_bounds__(256, 2) void attn_kernel(const unsigned short* __restrict__ xT,
                                                      const float* __restrict__ mus,
                                                      const float* __restrict__ sigma,
                                                      const int* __restrict__ pad,
                                                      float* __restrict__ out) {
    __shared__ unsigned short xt[D_][40];   // 40 KB
    __shared__ float rsm[4][16];

    const int jt = (gridDim.x - 1) - blockIdx.x;
    const int b = blockIdx.y;
    const int tid = threadIdx.x;
    const int w = tid >> 6;
    const int l = tid & 63;
    const int lo = l & 15, hi = l >> 4;
    const int jw0 = jt * 64 + w * 16;
    const float invL = 1.f / (float)pad[b];

    const int jA = jw0 + lo;
    const float mu = mus[(size_t)b * S_ + jA];
    const float sg = sigma[(size_t)b * S_ + jA];
    const float nis = -1.f / (2.f * sg * sg + 0.001f);

    f32x4 acc[32];
#pragma unroll
    for (int dt = 0; dt < 32; ++dt) acc[dt] = (f32x4){0.f, 0.f, 0.f, 0.f};

    const unsigned short* xTb = xT + (size_t)b * D_ * S_;
    float rs = 0.f;
    const int kend = (jt + 1) * 64;

    for (int k0 = 0; k0 < kend; k0 += 32) {
        uint4 v[2][4];
#pragma unroll
        for (int rr = 0; rr < 2; ++rr) {
            const int d = tid + rr * 256;
            const uint4* src = (const uint4*)(xTb + (size_t)d * S_ + k0);
#pragma unroll
            for (int i = 0; i < 4; ++i) v[rr][i] = src[i];
        }
        __syncthreads();
#pragma unroll
        for (int rr = 0; rr < 2; ++rr) {
            const int d = tid + rr * 256;
#pragma unroll
            for (int i = 0; i < 4; ++i) *(uint4*)&xt[d][i * 8] = v[rr][i];
        }
        __syncthreads();

        short8v a;
#pragma unroll
        for (int e = 0; e < 8; ++e) {
            const int k = k0 + hi * 8 + e;
            const float dd = (float)k * invL - mu;
            const float wv = (k <= jA) ? __expf(dd * dd * nis) : 0.f;
            rs += wv;
            a[e] = (short)f2bf(wv);
        }
#pragma unroll
        for (int dt = 0; dt < 32; ++dt) {
            const short8v bf = *(const short8v*)&xt[dt * 16 + lo][hi * 8];
            acc[dt] = __builtin_amdgcn_mfma_f32_16x16x32_bf16(a, bf, acc[dt], 0, 0, 0);
        }
    }

    rs += __shfl_xor(rs, 16);
    rs += __shfl_xor(rs, 32);
    if (l < 16) rsm[w][l] = rs;
    __syncthreads();

#pragma unroll
    for (int r = 0; r < 4; ++r) {
        const int j = jw0 + hi * 4 + r;
        const float rcp = 1.f / fmaxf(rsm[w][hi * 4 + r], 1e-12f);
        float* ob = out + ((size_t)b * S_ + j) * D_ + lo;
#pragma unroll
        for (int dt = 0; dt < 32; ++dt) {
            ob[dt * 16] = acc[dt][r] * rcp;
        }
    }
}

extern "C" void kernel_launch(void* const* d_in, const int* in_sizes, int n_in,
                              void* d_out, int out_size, void* d_ws, size_t ws_size,
                              hipStream_t stream) {
    const float* x     = (const float*)d_in[0];
    const int*   pad   = (const int*)d_in[1];
    const float* W_ih  = (const float*)d_in[2];
    const float* W_hh  = (const float*)d_in[3];
    const float* b_ih  = (const float*)d_in[4];
    const float* b_hh  = (const float*)d_in[5];
    const float* W_mu  = (const float*)d_in[6];
    const float* b_mu  = (const float*)d_in[7];
    const float* W_sig = (const float*)d_in[8];
    const float* b_sig = (const float*)d_in[9];
    float* out = (float*)d_out;

    float* xw    = (float*)d_ws;
    float* mus   = xw + (size_t)B_ * S_ * G_;
    float* sigma = mus + (size_t)B_ * S_;
    unsigned short* xT = (unsigned short*)(sigma + (size_t)B_ * S_);

    xw_kernel<<<(B_ * S_) / 64, 256, 0, stream>>>(x, W_ih, b_ih, b_hh, xw);
    conv_kernel<<<dim3(S_ / 64, D_ / 64, B_), 256, 0, stream>>>(x, xT);
    lstm_kernel<<<B_, 64, 0, stream>>>(xw, W_hh, W_mu, b_mu, W_sig, b_sig, pad, mus, sigma);
    attn_kernel<<<dim3(S_ / 64, B_), 256, 0, stream>>>(xT, mus, sigma, pad, out);
}